// Round 4
// baseline (1140.803 us; speedup 1.0000x reference)
//
#include <hip/hip_runtime.h>

#define N  160
#define SX (N * N)
#define SY N

typedef float f4 __attribute__((ext_vector_type(4)));

__device__ __forceinline__ f4 ld4(const float* __restrict__ p) {
    return *(const f4* __restrict__)p;
}

// 6-wide z-array: elements 0..5 hold F at z = zb-1 .. zb+4, clamp semantics
// (elem0 = F[zb] when zb==0, elem5 = F[zb+3] when zb+4 > 159). Halo elements
// via clamped scalar loads (hit lines fetched by adjacent lanes).
struct A6 { float v[6]; };

__device__ __forceinline__ A6 ld6(const float* __restrict__ p, int base, int tx) {
    A6 a;
    f4 c = ld4(p + base);
    a.v[1] = c.x; a.v[2] = c.y; a.v[3] = c.z; a.v[4] = c.w;
    a.v[0] = (tx > 0)  ? p[base - 1] : c.x;
    a.v[5] = (tx < 39) ? p[base + 4] : c.w;
    return a;
}

// block (40,8) = 320 threads = 5 waves. launch_bounds(320,6): cap VGPRs at
// ~84 so 6 waves/EU (24 waves/CU) are resident — round 3 hit 116 VGPRs and
// collapsed to ~4 waves/CU (13% occupancy), pure latency-bound regression.
__global__ __launch_bounds__(320, 6) void piano_energy_kernel(
    const float* __restrict__ C,   const float* __restrict__ Vx,
    const float* __restrict__ Vy,  const float* __restrict__ Vz,
    const float* __restrict__ Dxx, const float* __restrict__ Dxy,
    const float* __restrict__ Dxz, const float* __restrict__ Dyy,
    const float* __restrict__ Dyz, const float* __restrict__ Dzz,
    float* __restrict__ out)
{
    const int tx = threadIdx.x;                 // z-quad index 0..39
    const int zb = tx * 4;
    const int y  = blockIdx.y * 8 + threadIdx.y;
    const int x  = blockIdx.x;                  // block-uniform
    const int b  = blockIdx.z;
    const int idx = ((b * N + x) * N + y) * N + zb;

    const bool xlo = (x > 0), xhi = (x < N - 1);
    const bool ylo = (y > 0), yhi = (y < N - 1);

    const int oxp = xhi ? SX : 0,  oxm = xlo ? -SX : 0;
    const int oyp = yhi ? SY : 0,  oym = ylo ? -SY : 0;
    const float sxs = (xlo && xhi) ? 0.5f : 1.f;
    const float sys = (ylo && yhi) ? 0.5f : 1.f;

    // ---- persistent C z-arrays (the only large live state) ----
    A6 cc  = ld6(C, idx,       tx);
    A6 cxp = ld6(C, idx + oxp, tx);
    A6 cxm = ld6(C, idx + oxm, tx);
    A6 cyp = ld6(C, idx + oyp, tx);
    A6 cym = ld6(C, idx + oym, tx);

    // ---- pure second derivatives along x/y (consume the rare +2 loads now) ----
    float sXX[4], sYY[4];
    if (!xhi) {
#pragma unroll
        for (int j = 0; j < 4; ++j) sXX[j] = 0.f;
    } else if (xlo) {
#pragma unroll
        for (int j = 0; j < 4; ++j)
            sXX[j] = cxp.v[j + 1] - 2.f * cc.v[j + 1] + cxm.v[j + 1];
    } else {
        f4 cx2 = ld4(C + idx + 2 * SX);
#pragma unroll
        for (int j = 0; j < 4; ++j)
            sXX[j] = cx2[j] - 2.f * cxp.v[j + 1] + cc.v[j + 1];
    }
    if (!yhi) {
#pragma unroll
        for (int j = 0; j < 4; ++j) sYY[j] = 0.f;
    } else if (ylo) {
#pragma unroll
        for (int j = 0; j < 4; ++j)
            sYY[j] = cyp.v[j + 1] - 2.f * cc.v[j + 1] + cym.v[j + 1];
    } else {
        f4 cy2 = ld4(C + idx + 2 * SY);
#pragma unroll
        for (int j = 0; j < 4; ++j)
            sYY[j] = cy2[j] - 2.f * cyp.v[j + 1] + cc.v[j + 1];
    }

    // ---- advection first (V registers die at end of block) ----
    float res[4];
    {
        f4 vxc = ld4(Vx + idx), vxp = ld4(Vx + idx + oxp), vxm = ld4(Vx + idx + oxm);
        f4 vyc = ld4(Vy + idx), vyp = ld4(Vy + idx + oyp), vym = ld4(Vy + idx + oym);
        A6 vz6 = ld6(Vz, idx, tx);
#pragma unroll
        for (int j = 0; j < 4; ++j) {
            const int z = zb + j;
            const bool zbot = (z == 0), ztop = (z == N - 1);
            const float szs = (zbot || ztop) ? 1.f : 0.5f;
            const float c0 = cc.v[j + 1];

            const float dVx = sxs * (vxp[j] - vxm[j]);
            const float dVy = sys * (vyp[j] - vym[j]);
            const float dVz = szs * (vz6.v[j + 2] - vz6.v[j]);

            const float Cxf = xhi  ? (cxp.v[j + 1] - c0) : (c0 - cxm.v[j + 1]);
            const float Cxb = xlo  ? (c0 - cxm.v[j + 1]) : (cxp.v[j + 1] - c0);
            const float Cyf = yhi  ? (cyp.v[j + 1] - c0) : (c0 - cym.v[j + 1]);
            const float Cyb = ylo  ? (c0 - cym.v[j + 1]) : (cyp.v[j + 1] - c0);
            const float Czf = ztop ? (c0 - cc.v[j])      : (cc.v[j + 2] - c0);
            const float Czb = zbot ? (cc.v[j + 2] - c0)  : (c0 - cc.v[j]);

            const float C_x = (vxc[j] > 0.f) ? Cxb : Cxf;
            const float C_y = (vyc[j] > 0.f) ? Cyb : Cyf;
            const float C_z = (vz6.v[j + 1] > 0.f) ? Czb : Czf;

            res[j] = -(vxc[j] * C_x + vyc[j] * C_y + vz6.v[j + 1] * C_z)
                   - c0 * (dVx + dVy + dVz);
        }
    }

    // ---- central first derivatives (persistent, reused by all 6 D terms) ----
    float Cxc[4], Cyc[4], Czc[4];
#pragma unroll
    for (int j = 0; j < 4; ++j) {
        const int z = zb + j;
        const float szs = (z == 0 || z == N - 1) ? 1.f : 0.5f;
        Cxc[j] = sxs * (cxp.v[j + 1] - cxm.v[j + 1]);
        Cyc[j] = sys * (cyp.v[j + 1] - cym.v[j + 1]);
        Czc[j] = szs * (cc.v[j + 2] - cc.v[j]);
    }

    // ---- cross-xy combos then Dxy (cXY dies here) ----
    {
        const int obx1 = xlo ? 0 : SX,  obx0 = obx1 - SX;
        const int oby1 = ylo ? 0 : SY,  oby0 = oby1 - SY;
        const int ofxp = oxp,           ofx0 = xhi ? 0 : -SX;
        const int ofyp = oyp,           ofy0 = yhi ? 0 : -SY;

        float cXY[4];
        {
            f4 qa = ld4(C + idx + obx1 + ofyp), qb = ld4(C + idx + obx1 + ofy0);
            f4 qc = ld4(C + idx + obx0 + ofyp), qd = ld4(C + idx + obx0 + ofy0);
#pragma unroll
            for (int j = 0; j < 4; ++j)
                cXY[j] = (qa[j] - qb[j]) - (qc[j] - qd[j]);
        }
        {
            f4 qa = ld4(C + idx + oby1 + ofxp), qb = ld4(C + idx + oby1 + ofx0);
            f4 qc = ld4(C + idx + oby0 + ofxp), qd = ld4(C + idx + oby0 + ofx0);
#pragma unroll
            for (int j = 0; j < 4; ++j)
                cXY[j] += (qa[j] - qb[j]) - (qc[j] - qd[j]);
        }
        f4 dc  = ld4(Dxy + idx);
        f4 dxp_ = ld4(Dxy + idx + oxp), dxm_ = ld4(Dxy + idx + oxm);
        f4 dyp_ = ld4(Dxy + idx + oyp), dym_ = ld4(Dxy + idx + oym);
#pragma unroll
        for (int j = 0; j < 4; ++j)
            res[j] += sxs * (dxp_[j] - dxm_[j]) * Cyc[j]
                    + sys * (dyp_[j] - dym_[j]) * Cxc[j]
                    + dc[j] * cXY[j];
    }

    // ---- Dxx (sXX dies), Dyy (sYY dies) ----
    {
        f4 dc = ld4(Dxx + idx), dp = ld4(Dxx + idx + oxp), dm = ld4(Dxx + idx + oxm);
#pragma unroll
        for (int j = 0; j < 4; ++j)
            res[j] += sxs * (dp[j] - dm[j]) * Cxc[j] + dc[j] * sXX[j];
    }
    {
        f4 dc = ld4(Dyy + idx), dp = ld4(Dyy + idx + oyp), dm = ld4(Dyy + idx + oym);
#pragma unroll
        for (int j = 0; j < 4; ++j)
            res[j] += sys * (dp[j] - dm[j]) * Cyc[j] + dc[j] * sYY[j];
    }

    // ---- Dzz (sZZ inline from cc) ----
    {
        A6 d6 = ld6(Dzz, idx, tx);
#pragma unroll
        for (int j = 0; j < 4; ++j) {
            const int z = zb + j;
            const bool zbot = (z == 0), ztop = (z == N - 1);
            const float szs = (zbot || ztop) ? 1.f : 0.5f;
            const float sZZ = ztop ? 0.f
                            : (!zbot ? (cc.v[j + 2] - 2.f * cc.v[j + 1] + cc.v[j])
                                     : (cc.v[3] - 2.f * cc.v[2] + cc.v[1]));
            res[j] += szs * (d6.v[j + 2] - d6.v[j]) * Czc[j] + d6.v[j + 1] * sZZ;
        }
    }

    // ---- Dxz: crossZX + crossXZ inline from A6s ----
    {
        A6 d6 = ld6(Dxz, idx, tx);
        f4 dp = ld4(Dxz + idx + oxp), dm = ld4(Dxz + idx + oxm);
#pragma unroll
        for (int j = 0; j < 4; ++j) {
            const int z = zb + j;
            const bool zbot = (z == 0), ztop = (z == N - 1);
            const float szs = (zbot || ztop) ? 1.f : 0.5f;
            // gX(k) = forward-x diff at z-element k
            auto gX = [&](int k) {
                return xhi ? (cxp.v[k] - cc.v[k]) : (cc.v[k] - cxm.v[k]);
            };
            const float zx = zbot ? (gX(j + 2) - gX(j + 1)) : (gX(j + 1) - gX(j));
            const float fzcc = ztop ? (cc.v[j + 1] - cc.v[j])  : (cc.v[j + 2] - cc.v[j + 1]);
            const float fzxp = ztop ? (cxp.v[j + 1] - cxp.v[j]) : (cxp.v[j + 2] - cxp.v[j + 1]);
            const float fzxm = ztop ? (cxm.v[j + 1] - cxm.v[j]) : (cxm.v[j + 2] - cxm.v[j + 1]);
            const float xz = xlo ? (fzcc - fzxm) : (fzxp - fzcc);
            res[j] += sxs * (dp[j] - dm[j]) * Czc[j]
                    + szs * (d6.v[j + 2] - d6.v[j]) * Cxc[j]
                    + d6.v[j + 1] * (zx + xz);
        }
    }

    // ---- Dyz: crossZY + crossYZ inline from A6s ----
    {
        A6 d6 = ld6(Dyz, idx, tx);
        f4 dp = ld4(Dyz + idx + oyp), dm = ld4(Dyz + idx + oym);
#pragma unroll
        for (int j = 0; j < 4; ++j) {
            const int z = zb + j;
            const bool zbot = (z == 0), ztop = (z == N - 1);
            const float szs = (zbot || ztop) ? 1.f : 0.5f;
            auto gY = [&](int k) {
                return yhi ? (cyp.v[k] - cc.v[k]) : (cc.v[k] - cym.v[k]);
            };
            const float zy = zbot ? (gY(j + 2) - gY(j + 1)) : (gY(j + 1) - gY(j));
            const float fzcc = ztop ? (cc.v[j + 1] - cc.v[j])  : (cc.v[j + 2] - cc.v[j + 1]);
            const float fzyp = ztop ? (cyp.v[j + 1] - cyp.v[j]) : (cyp.v[j + 2] - cyp.v[j + 1]);
            const float fzym = ztop ? (cym.v[j + 1] - cym.v[j]) : (cym.v[j + 2] - cym.v[j + 1]);
            const float yz = ylo ? (fzcc - fzym) : (fzyp - fzcc);
            res[j] += sys * (dp[j] - dm[j]) * Czc[j]
                    + szs * (d6.v[j + 2] - d6.v[j]) * Cyc[j]
                    + d6.v[j + 1] * (zy + yz);
        }
    }

    f4 o;
    o.x = res[0]; o.y = res[1]; o.z = res[2]; o.w = res[3];
    *(f4*)(out + idx) = o;
}

extern "C" void kernel_launch(void* const* d_in, const int* in_sizes, int n_in,
                              void* d_out, int out_size, void* d_ws, size_t ws_size,
                              hipStream_t stream) {
    const float* C   = (const float*)d_in[0];
    const float* Vx  = (const float*)d_in[1];
    const float* Vy  = (const float*)d_in[2];
    const float* Vz  = (const float*)d_in[3];
    const float* Dxx = (const float*)d_in[4];
    const float* Dxy = (const float*)d_in[5];
    const float* Dxz = (const float*)d_in[6];
    const float* Dyy = (const float*)d_in[7];
    const float* Dyz = (const float*)d_in[8];
    const float* Dzz = (const float*)d_in[9];
    float* out = (float*)d_out;

    dim3 grid(N, N / 8, 2);
    dim3 block(N / 4, 8, 1);
    hipLaunchKernelGGL(piano_energy_kernel, grid, block, 0, stream,
                       C, Vx, Vy, Vz, Dxx, Dxy, Dxz, Dyy, Dyz, Dzz, out);
}

// Round 5
// 429.975 us; speedup vs baseline: 2.6532x; 2.6532x over previous
//
#include <hip/hip_runtime.h>

#define N  160
#define SX (N * N)
#define SY N

typedef float f2 __attribute__((ext_vector_type(2)));

__device__ __forceinline__ f2 ld2(const float* __restrict__ p) {
    return *(const f2* __restrict__)p;
}

// 4-wide z-array: elements 0..3 hold F at z = zb-1 .. zb+2, clamp semantics
// (elem0 = F[zb] when zb==0, elem3 = F[zb+1] when zb+2 > 159). Halos via
// clamped scalar loads (hit cache lines fetched by adjacent lanes). No
// shuffles, so the 80-lane row vs 64-lane wave seam is irrelevant.
// f2 (not f4) on purpose: round-3's f4 version needed ~116 live VGPRs
// (13% occupancy, 197 us); round-4's forced cap to 40 VGPRs spilled 3.5 GB
// of scratch traffic (969 us). Halving per-thread state is the fix.
struct A4 { float v[4]; };

__device__ __forceinline__ A4 ld4z(const float* __restrict__ p, int base, int tx) {
    A4 a;
    f2 c = ld2(p + base);
    a.v[1] = c.x; a.v[2] = c.y;
    a.v[0] = (tx > 0)  ? p[base - 1] : c.x;
    a.v[3] = (tx < 79) ? p[base + 2] : c.y;
    return a;
}

__global__ __launch_bounds__(320) void piano_energy_kernel(
    const float* __restrict__ C,   const float* __restrict__ Vx,
    const float* __restrict__ Vy,  const float* __restrict__ Vz,
    const float* __restrict__ Dxx, const float* __restrict__ Dxy,
    const float* __restrict__ Dxz, const float* __restrict__ Dyy,
    const float* __restrict__ Dyz, const float* __restrict__ Dzz,
    float* __restrict__ out)
{
    const int tx = threadIdx.x;                 // z-pair index 0..79
    const int zb = tx * 2;
    const int y  = blockIdx.y * 4 + threadIdx.y;
    const int x  = blockIdx.x;                  // block-uniform
    const int b  = blockIdx.z;
    const int idx = ((b * N + x) * N + y) * N + zb;

    const bool xlo = (x > 0), xhi = (x < N - 1);
    const bool ylo = (y > 0), yhi = (y < N - 1);

    const int oxp = xhi ? SX : 0,  oxm = xlo ? -SX : 0;
    const int oyp = yhi ? SY : 0,  oym = ylo ? -SY : 0;
    const float sxs = (xlo && xhi) ? 0.5f : 1.f;
    const float sys = (ylo && yhi) ? 0.5f : 1.f;

    // ---- persistent C z-arrays (the only large live state: 20 floats) ----
    A4 cc  = ld4z(C, idx,       tx);
    A4 cxp = ld4z(C, idx + oxp, tx);
    A4 cxm = ld4z(C, idx + oxm, tx);
    A4 cyp = ld4z(C, idx + oyp, tx);
    A4 cym = ld4z(C, idx + oym, tx);

    // ---- pure second derivatives along x/y (consume rare +2 loads now) ----
    float sXX[2], sYY[2];
    if (!xhi) {
#pragma unroll
        for (int j = 0; j < 2; ++j) sXX[j] = 0.f;
    } else if (xlo) {
#pragma unroll
        for (int j = 0; j < 2; ++j)
            sXX[j] = cxp.v[j + 1] - 2.f * cc.v[j + 1] + cxm.v[j + 1];
    } else {
        f2 cx2 = ld2(C + idx + 2 * SX);
#pragma unroll
        for (int j = 0; j < 2; ++j)
            sXX[j] = cx2[j] - 2.f * cxp.v[j + 1] + cc.v[j + 1];
    }
    if (!yhi) {
#pragma unroll
        for (int j = 0; j < 2; ++j) sYY[j] = 0.f;
    } else if (ylo) {
#pragma unroll
        for (int j = 0; j < 2; ++j)
            sYY[j] = cyp.v[j + 1] - 2.f * cc.v[j + 1] + cym.v[j + 1];
    } else {
        f2 cy2 = ld2(C + idx + 2 * SY);
#pragma unroll
        for (int j = 0; j < 2; ++j)
            sYY[j] = cy2[j] - 2.f * cyp.v[j + 1] + cc.v[j + 1];
    }

    // ---- advection first (V registers die at end of block) ----
    float res[2];
    {
        f2 vxc = ld2(Vx + idx), vxp = ld2(Vx + idx + oxp), vxm = ld2(Vx + idx + oxm);
        f2 vyc = ld2(Vy + idx), vyp = ld2(Vy + idx + oyp), vym = ld2(Vy + idx + oym);
        A4 vz4 = ld4z(Vz, idx, tx);
#pragma unroll
        for (int j = 0; j < 2; ++j) {
            const int z = zb + j;
            const bool zbot = (z == 0), ztop = (z == N - 1);
            const float szs = (zbot || ztop) ? 1.f : 0.5f;
            const float c0 = cc.v[j + 1];

            const float dVx = sxs * (vxp[j] - vxm[j]);
            const float dVy = sys * (vyp[j] - vym[j]);
            const float dVz = szs * (vz4.v[j + 2] - vz4.v[j]);

            const float Cxf = xhi  ? (cxp.v[j + 1] - c0) : (c0 - cxm.v[j + 1]);
            const float Cxb = xlo  ? (c0 - cxm.v[j + 1]) : (cxp.v[j + 1] - c0);
            const float Cyf = yhi  ? (cyp.v[j + 1] - c0) : (c0 - cym.v[j + 1]);
            const float Cyb = ylo  ? (c0 - cym.v[j + 1]) : (cyp.v[j + 1] - c0);
            const float Czf = ztop ? (c0 - cc.v[j])      : (cc.v[j + 2] - c0);
            const float Czb = zbot ? (cc.v[j + 2] - c0)  : (c0 - cc.v[j]);

            const float C_x = (vxc[j] > 0.f) ? Cxb : Cxf;
            const float C_y = (vyc[j] > 0.f) ? Cyb : Cyf;
            const float C_z = (vz4.v[j + 1] > 0.f) ? Czb : Czf;

            res[j] = -(vxc[j] * C_x + vyc[j] * C_y + vz4.v[j + 1] * C_z)
                   - c0 * (dVx + dVy + dVz);
        }
    }

    // ---- central first derivatives (reused by all 6 D terms) ----
    float Cxc[2], Cyc[2], Czc[2];
#pragma unroll
    for (int j = 0; j < 2; ++j) {
        const int z = zb + j;
        const float szs = (z == 0 || z == N - 1) ? 1.f : 0.5f;
        Cxc[j] = sxs * (cxp.v[j + 1] - cxm.v[j + 1]);
        Cyc[j] = sys * (cyp.v[j + 1] - cym.v[j + 1]);
        Czc[j] = szs * (cc.v[j + 2] - cc.v[j]);
    }

    // ---- cross-xy combos then Dxy (cXY dies here) ----
    {
        const int obx1 = xlo ? 0 : SX,  obx0 = obx1 - SX;
        const int oby1 = ylo ? 0 : SY,  oby0 = oby1 - SY;
        const int ofxp = oxp,           ofx0 = xhi ? 0 : -SX;
        const int ofyp = oyp,           ofy0 = yhi ? 0 : -SY;

        float cXY[2];
        {
            f2 qa = ld2(C + idx + obx1 + ofyp), qb = ld2(C + idx + obx1 + ofy0);
            f2 qc = ld2(C + idx + obx0 + ofyp), qd = ld2(C + idx + obx0 + ofy0);
#pragma unroll
            for (int j = 0; j < 2; ++j)
                cXY[j] = (qa[j] - qb[j]) - (qc[j] - qd[j]);
        }
        {
            f2 qa = ld2(C + idx + oby1 + ofxp), qb = ld2(C + idx + oby1 + ofx0);
            f2 qc = ld2(C + idx + oby0 + ofxp), qd = ld2(C + idx + oby0 + ofx0);
#pragma unroll
            for (int j = 0; j < 2; ++j)
                cXY[j] += (qa[j] - qb[j]) - (qc[j] - qd[j]);
        }
        f2 dc  = ld2(Dxy + idx);
        f2 dxp_ = ld2(Dxy + idx + oxp), dxm_ = ld2(Dxy + idx + oxm);
        f2 dyp_ = ld2(Dxy + idx + oyp), dym_ = ld2(Dxy + idx + oym);
#pragma unroll
        for (int j = 0; j < 2; ++j)
            res[j] += sxs * (dxp_[j] - dxm_[j]) * Cyc[j]
                    + sys * (dyp_[j] - dym_[j]) * Cxc[j]
                    + dc[j] * cXY[j];
    }

    // ---- Dxx (sXX dies), Dyy (sYY dies) ----
    {
        f2 dc = ld2(Dxx + idx), dp = ld2(Dxx + idx + oxp), dm = ld2(Dxx + idx + oxm);
#pragma unroll
        for (int j = 0; j < 2; ++j)
            res[j] += sxs * (dp[j] - dm[j]) * Cxc[j] + dc[j] * sXX[j];
    }
    {
        f2 dc = ld2(Dyy + idx), dp = ld2(Dyy + idx + oyp), dm = ld2(Dyy + idx + oym);
#pragma unroll
        for (int j = 0; j < 2; ++j)
            res[j] += sys * (dp[j] - dm[j]) * Cyc[j] + dc[j] * sYY[j];
    }

    // ---- Dzz (sZZ inline from cc) ----
    {
        A4 d4 = ld4z(Dzz, idx, tx);
#pragma unroll
        for (int j = 0; j < 2; ++j) {
            const int z = zb + j;
            const bool zbot = (z == 0), ztop = (z == N - 1);
            const float szs = (zbot || ztop) ? 1.f : 0.5f;
            const float sZZ = ztop ? 0.f
                            : (!zbot ? (cc.v[j + 2] - 2.f * cc.v[j + 1] + cc.v[j])
                                     : (cc.v[3] - 2.f * cc.v[2] + cc.v[1]));
            res[j] += szs * (d4.v[j + 2] - d4.v[j]) * Czc[j] + d4.v[j + 1] * sZZ;
        }
    }

    // ---- Dxz: crossZX + crossXZ inline from A4s ----
    {
        A4 d4 = ld4z(Dxz, idx, tx);
        f2 dp = ld2(Dxz + idx + oxp), dm = ld2(Dxz + idx + oxm);
#pragma unroll
        for (int j = 0; j < 2; ++j) {
            const int z = zb + j;
            const bool zbot = (z == 0), ztop = (z == N - 1);
            const float szs = (zbot || ztop) ? 1.f : 0.5f;
            auto gX = [&](int k) {
                return xhi ? (cxp.v[k] - cc.v[k]) : (cc.v[k] - cxm.v[k]);
            };
            const float zx = zbot ? (gX(j + 2) - gX(j + 1)) : (gX(j + 1) - gX(j));
            const float fzcc = ztop ? (cc.v[j + 1] - cc.v[j])   : (cc.v[j + 2] - cc.v[j + 1]);
            const float fzxp = ztop ? (cxp.v[j + 1] - cxp.v[j]) : (cxp.v[j + 2] - cxp.v[j + 1]);
            const float fzxm = ztop ? (cxm.v[j + 1] - cxm.v[j]) : (cxm.v[j + 2] - cxm.v[j + 1]);
            const float xz = xlo ? (fzcc - fzxm) : (fzxp - fzcc);
            res[j] += sxs * (dp[j] - dm[j]) * Czc[j]
                    + szs * (d4.v[j + 2] - d4.v[j]) * Cxc[j]
                    + d4.v[j + 1] * (zx + xz);
        }
    }

    // ---- Dyz: crossZY + crossYZ inline from A4s ----
    {
        A4 d4 = ld4z(Dyz, idx, tx);
        f2 dp = ld2(Dyz + idx + oyp), dm = ld2(Dyz + idx + oym);
#pragma unroll
        for (int j = 0; j < 2; ++j) {
            const int z = zb + j;
            const bool zbot = (z == 0), ztop = (z == N - 1);
            const float szs = (zbot || ztop) ? 1.f : 0.5f;
            auto gY = [&](int k) {
                return yhi ? (cyp.v[k] - cc.v[k]) : (cc.v[k] - cym.v[k]);
            };
            const float zy = zbot ? (gY(j + 2) - gY(j + 1)) : (gY(j + 1) - gY(j));
            const float fzcc = ztop ? (cc.v[j + 1] - cc.v[j])   : (cc.v[j + 2] - cc.v[j + 1]);
            const float fzyp = ztop ? (cyp.v[j + 1] - cyp.v[j]) : (cyp.v[j + 2] - cyp.v[j + 1]);
            const float fzym = ztop ? (cym.v[j + 1] - cym.v[j]) : (cym.v[j + 2] - cym.v[j + 1]);
            const float yz = ylo ? (fzcc - fzym) : (fzyp - fzcc);
            res[j] += sys * (dp[j] - dm[j]) * Czc[j]
                    + szs * (d4.v[j + 2] - d4.v[j]) * Cyc[j]
                    + d4.v[j + 1] * (zy + yz);
        }
    }

    f2 o;
    o.x = res[0]; o.y = res[1];
    *(f2*)(out + idx) = o;
}

extern "C" void kernel_launch(void* const* d_in, const int* in_sizes, int n_in,
                              void* d_out, int out_size, void* d_ws, size_t ws_size,
                              hipStream_t stream) {
    const float* C   = (const float*)d_in[0];
    const float* Vx  = (const float*)d_in[1];
    const float* Vy  = (const float*)d_in[2];
    const float* Vz  = (const float*)d_in[3];
    const float* Dxx = (const float*)d_in[4];
    const float* Dxy = (const float*)d_in[5];
    const float* Dxz = (const float*)d_in[6];
    const float* Dyy = (const float*)d_in[7];
    const float* Dyz = (const float*)d_in[8];
    const float* Dzz = (const float*)d_in[9];
    float* out = (float*)d_out;

    dim3 grid(N, N / 4, 2);
    dim3 block(N / 2, 4, 1);   // 320 threads = 5 waves; lanes contiguous in z
    hipLaunchKernelGGL(piano_energy_kernel, grid, block, 0, stream,
                       C, Vx, Vy, Vz, Dxx, Dxy, Dxz, Dyy, Dyz, Dzz, out);
}

// Round 6
// 354.063 us; speedup vs baseline: 3.2220x; 1.2144x over previous
//
#include <hip/hip_runtime.h>

#define N   160
#define SX  (N * N)
#define SY  N

// One voxel/thread, scalar loads, minimal registers (round-1 structure: the
// empirical optimum — VGPR=32/occ 53% beat every register-heavy variant).
// Round-6 changes vs round-1:
//  * interior cross-terms use the algebraic 2-corner reduction (8 loads -> 2)
//  * x lives in blockIdx.y (gridDim.x = 40 = 0 mod 8) so x+-1 neighbor blocks
//    map to the same XCD -> x-plane reuse hits local L2.
__global__ __launch_bounds__(640) void piano_energy_kernel(
    const float* __restrict__ C,   const float* __restrict__ Vx,
    const float* __restrict__ Vy,  const float* __restrict__ Vz,
    const float* __restrict__ Dxx, const float* __restrict__ Dxy,
    const float* __restrict__ Dxz, const float* __restrict__ Dyy,
    const float* __restrict__ Dyz, const float* __restrict__ Dzz,
    float* __restrict__ out)
{
    const int z = threadIdx.x;                       // 0..159 (contiguous axis)
    const int y = blockIdx.x * 4 + threadIdx.y;      // 0..159 (one y per wave)
    const int x = blockIdx.y;                        // 0..159 (block-uniform)
    const int b = blockIdx.z;                        // 0..1

    const int idx = ((b * N + x) * N + y) * N + z;

    const bool xlo = (x > 0), xhi = (x < N - 1);
    const bool ylo = (y > 0), yhi = (y < N - 1);
    const bool zlo = (z > 0), zhi = (z < N - 1);

    const int oxp = xhi ?  SX : 0,  oxm = xlo ? -SX : 0;
    const int oyp = yhi ?  SY : 0,  oym = ylo ? -SY : 0;
    const int ozp = zhi ?   1 : 0,  ozm = zlo ?  -1 : 0;

    const float sx = (xlo && xhi) ? 0.5f : 1.f;
    const float sy = (ylo && yhi) ? 0.5f : 1.f;
    const float sz = (zlo && zhi) ? 0.5f : 1.f;

    // ---- C face neighborhood (7 loads) ----
    const float c0  = C[idx];
    const float cxp = C[idx + oxp], cxm = C[idx + oxm];
    const float cyp = C[idx + oyp], cym = C[idx + oym];
    const float czp = C[idx + ozp], czm = C[idx + ozm];

    // first derivatives of C
    const float Cx_c = sx * (cxp - cxm);
    const float Cy_c = sy * (cyp - cym);
    const float Cz_c = sz * (czp - czm);
    const float Cx_f = xhi ? (cxp - c0) : (c0 - cxm);
    const float Cy_f = yhi ? (cyp - c0) : (c0 - cym);
    const float Cz_f = zhi ? (czp - c0) : (c0 - czm);
    const float Cx_b = xlo ? (c0 - cxm) : (cxp - c0);
    const float Cy_b = ylo ? (c0 - cym) : (cyp - c0);
    const float Cz_b = zlo ? (c0 - czm) : (czp - c0);

    // pure second derivatives  dAb(CA_f)
    float sXX, sYY, sZZ;
    if (!xhi)      sXX = 0.f;
    else if (xlo)  sXX = cxp - 2.f * c0 + cxm;
    else           sXX = C[idx + 2 * SX] - 2.f * cxp + c0;
    if (!yhi)      sYY = 0.f;
    else if (ylo)  sYY = cyp - 2.f * c0 + cym;
    else           sYY = C[idx + 2 * SY] - 2.f * cyp + c0;
    if (!zhi)      sZZ = 0.f;
    else if (zlo)  sZZ = czp - 2.f * c0 + czm;
    else           sZZ = C[idx + 2] - 2.f * czp + c0;

    // ---- cross second-derivative sums; interior = 2-corner reduction ----
    // generic backward/forward offset pieces (round-1 form, for boundary path)
    const int obx1 = xlo ? 0 : SX,  obx0 = obx1 - SX;
    const int oby1 = ylo ? 0 : SY,  oby0 = oby1 - SY;
    const int obz1 = zlo ? 0 : 1,   obz0 = obz1 - 1;
    const int ofx0 = xhi ? 0 : -SX;
    const int ofy0 = yhi ? 0 : -SY;
    const int ofz0 = zhi ? 0 : -1;

    float cXY;  // crossXY + crossYX   (x Dxy)
    if (xlo && xhi && ylo && yhi) {   // wave-uniform branch
        cXY = cxp + cxm + cyp + cym - 2.f * c0
            - C[idx - SX + SY] - C[idx + SX - SY];
    } else {
        cXY = (C[idx + obx1 + oyp] - C[idx + obx1 + ofy0])
            - (C[idx + obx0 + oyp] - C[idx + obx0 + ofy0])
            + (C[idx + oby1 + oxp] - C[idx + oby1 + ofx0])
            - (C[idx + oby0 + oxp] - C[idx + oby0 + ofx0]);
    }

    float cXZ;  // crossZX + crossXZ   (x Dxz)
    if (xlo && xhi && zlo && zhi) {   // divergent only in z-boundary waves
        cXZ = cxp + cxm + czp + czm - 2.f * c0
            - C[idx + SX - 1] - C[idx - SX + 1];
    } else {
        cXZ = (C[idx + obz1 + oxp] - C[idx + obz1 + ofx0])
            - (C[idx + obz0 + oxp] - C[idx + obz0 + ofx0])
            + (C[idx + obx1 + ozp] - C[idx + obx1 + ofz0])
            - (C[idx + obx0 + ozp] - C[idx + obx0 + ofz0]);
    }

    float cYZ;  // crossZY + crossYZ   (x Dyz)
    if (ylo && yhi && zlo && zhi) {
        cYZ = cyp + cym + czp + czm - 2.f * c0
            - C[idx + SY - 1] - C[idx - SY + 1];
    } else {
        cYZ = (C[idx + obz1 + oyp] - C[idx + obz1 + ofy0])
            - (C[idx + obz0 + oyp] - C[idx + obz0 + ofy0])
            + (C[idx + oby1 + ozp] - C[idx + oby1 + ofz0])
            - (C[idx + oby0 + ozp] - C[idx + oby0 + ofz0]);
    }

    // ---- diffusion-tensor divergence terms (central diffs of D) ----
    const float dDxx_x = sx * (Dxx[idx + oxp] - Dxx[idx + oxm]);
    const float dDxy_x = sx * (Dxy[idx + oxp] - Dxy[idx + oxm]);
    const float dDxy_y = sy * (Dxy[idx + oyp] - Dxy[idx + oym]);
    const float dDxz_x = sx * (Dxz[idx + oxp] - Dxz[idx + oxm]);
    const float dDxz_z = sz * (Dxz[idx + ozp] - Dxz[idx + ozm]);
    const float dDyy_y = sy * (Dyy[idx + oyp] - Dyy[idx + oym]);
    const float dDyz_y = sy * (Dyz[idx + oyp] - Dyz[idx + oym]);
    const float dDyz_z = sz * (Dyz[idx + ozp] - Dyz[idx + ozm]);
    const float dDzz_z = sz * (Dzz[idx + ozp] - Dzz[idx + ozm]);

    const float t1 = dDxx_x + dDxy_y + dDxz_z;
    const float t2 = dDxy_x + dDyy_y + dDyz_z;
    const float t3 = dDxz_x + dDyz_y + dDzz_z;

    const float Dxx0 = Dxx[idx], Dyy0 = Dyy[idx], Dzz0 = Dzz[idx];
    const float Dxy0 = Dxy[idx], Dyz0 = Dyz[idx], Dxz0 = Dxz[idx];

    const float diff = t1 * Cx_c + t2 * Cy_c + t3 * Cz_c
                     + Dxx0 * sXX + Dyy0 * sYY + Dzz0 * sZZ
                     + Dxy0 * cXY + Dyz0 * cYZ + Dxz0 * cXZ;

    // ---- advection (upwind) ----
    const float Vx0 = Vx[idx], Vy0 = Vy[idx], Vz0 = Vz[idx];
    const float dVx = sx * (Vx[idx + oxp] - Vx[idx + oxm]);
    const float dVy = sy * (Vy[idx + oyp] - Vy[idx + oym]);
    const float dVz = sz * (Vz[idx + ozp] - Vz[idx + ozm]);

    const float C_x = (Vx0 > 0.f) ? Cx_b : Cx_f;
    const float C_y = (Vy0 > 0.f) ? Cy_b : Cy_f;
    const float C_z = (Vz0 > 0.f) ? Cz_b : Cz_f;

    const float adv = -(Vx0 * C_x + Vy0 * C_y + Vz0 * C_z)
                    - c0 * (dVx + dVy + dVz);

    out[idx] = diff + adv;
}

extern "C" void kernel_launch(void* const* d_in, const int* in_sizes, int n_in,
                              void* d_out, int out_size, void* d_ws, size_t ws_size,
                              hipStream_t stream) {
    const float* C   = (const float*)d_in[0];
    const float* Vx  = (const float*)d_in[1];
    const float* Vy  = (const float*)d_in[2];
    const float* Vz  = (const float*)d_in[3];
    const float* Dxx = (const float*)d_in[4];
    const float* Dxy = (const float*)d_in[5];
    const float* Dxz = (const float*)d_in[6];
    const float* Dyy = (const float*)d_in[7];
    const float* Dyz = (const float*)d_in[8];
    const float* Dzz = (const float*)d_in[9];
    float* out = (float*)d_out;

    // grid.x = y-tiles (40, = 0 mod 8) so x+-1 neighbors (blockIdx.y +-1)
    // land on the same XCD under round-robin dispatch -> x-plane L2 reuse.
    dim3 grid(N / 4, N, 2);
    dim3 block(N, 4, 1);
    hipLaunchKernelGGL(piano_energy_kernel, grid, block, 0, stream,
                       C, Vx, Vy, Vz, Dxx, Dxy, Dxz, Dyy, Dyz, Dzz, out);
}